// Round 1
// 404.032 us; speedup vs baseline: 1.0147x; 1.0147x over previous
//
#include <hip/hip_runtime.h>

typedef unsigned short u16;
typedef unsigned int u32;
typedef __attribute__((ext_vector_type(8))) __bf16 bf16x8;
typedef __attribute__((ext_vector_type(4))) float f32x4;

#define T_TOK 8192
#define DMODEL 2048
#define N_EXP 8
#define NT 32   // 2048 / BK, BK=64

// ---------- helpers ----------
__device__ __forceinline__ u32 f2bf_bits(float f) {
    u32 u = __builtin_bit_cast(u32, f);
    return (u + 0x7fffu + ((u >> 16) & 1u)) >> 16;   // RNE truncate to bf16
}
__device__ __forceinline__ u32 pack2(float a, float b) {
    return f2bf_bits(a) | (f2bf_bits(b) << 16);
}

__device__ __forceinline__ void load_lds16(const u16* g, u16* l) {
    void* gnc = (void*)g;
    __builtin_amdgcn_global_load_lds(
        (__attribute__((address_space(1))) void*)gnc,
        (__attribute__((address_space(3))) void*)l,
        16, 0, 0);
}

// ---------- kernel 0: zero padded counters ----------
__global__ void zero_kernel(u32* p) {
    p[threadIdx.x] = 0u;   // 256 x 4B = 1024 B (counts 512 + sumt 512)
}

// ---------- kernel 1: fused prep — blocks 0..511 router, 512..16895 W->bf16 ----------
__global__ void __launch_bounds__(256) prep_kernel(const float* __restrict__ x,
                                                   const float* __restrict__ Wr,
                                                   const float* __restrict__ br,
                                                   const float* __restrict__ W,
                                                   u16* __restrict__ Wb,
                                                   u16* __restrict__ xb,
                                                   int* __restrict__ perm,
                                                   float* __restrict__ topp,
                                                   int* __restrict__ counts,
                                                   float* __restrict__ sumt) {
    __shared__ int sEid[16];
    __shared__ float sTp[16];

    int bx = blockIdx.x;
    int tid = threadIdx.x;

    if (bx >= 512) {
        // ---- W fp32 -> bf16 (BW-bound, runs concurrently with router) ----
        size_t i = ((size_t)(bx - 512) * 256 + tid) * 8;
        float4 a = *(const float4*)(W + i);
        float4 c = *(const float4*)(W + i + 4);
        uint4 o;
        o.x = pack2(a.x, a.y);
        o.y = pack2(a.z, a.w);
        o.z = pack2(c.x, c.y);
        o.w = pack2(c.z, c.w);
        *(uint4*)(Wb + i) = o;
        return;
    }

    // ---- router: 4 tokens/wave ----
    int lane = tid & 63;
    int w = tid >> 6;
    int t0 = bx * 16 + w * 4;

    float acc[4][8];
#pragma unroll
    for (int tk = 0; tk < 4; tk++)
#pragma unroll
        for (int e = 0; e < 8; e++) acc[tk][e] = 0.0f;

#pragma unroll
    for (int i = 0; i < 8; i++) {
        int vidx = i * 64 + lane;
        float4 wv[8];
#pragma unroll
        for (int e = 0; e < 8; e++)
            wv[e] = *(const float4*)(Wr + e * DMODEL + vidx * 4);
#pragma unroll
        for (int tk = 0; tk < 4; tk++) {
            int t = t0 + tk;
            float4 xv = ((const float4*)(x + ((size_t)t << 11)))[vidx];
            uint2 pk;
            pk.x = pack2(xv.x, xv.y);
            pk.y = pack2(xv.z, xv.w);
            *(uint2*)(xb + ((size_t)t << 11) + (size_t)vidx * 4) = pk;
#pragma unroll
            for (int e = 0; e < 8; e++) {
                acc[tk][e] = fmaf(xv.x, wv[e].x, fmaf(xv.y, wv[e].y,
                              fmaf(xv.z, wv[e].z, fmaf(xv.w, wv[e].w, acc[tk][e]))));
            }
        }
    }
#pragma unroll
    for (int off = 32; off; off >>= 1)
#pragma unroll
        for (int tk = 0; tk < 4; tk++)
#pragma unroll
            for (int e = 0; e < 8; e++)
                acc[tk][e] += __shfl_xor(acc[tk][e], off, 64);

    if (lane == 0) {
#pragma unroll
        for (int tk = 0; tk < 4; tk++) {
            float lg[8];
#pragma unroll
            for (int e = 0; e < 8; e++) lg[e] = acc[tk][e] + br[e];
            float m = lg[0];
            int am = 0;
#pragma unroll
            for (int e = 1; e < 8; e++)
                if (lg[e] > m) { m = lg[e]; am = e; }
            float s = 0.0f;
#pragma unroll
            for (int e = 0; e < 8; e++) s += __expf(lg[e] - m);
            float tp = 1.0f / s;
            sEid[w * 4 + tk] = am;
            sTp[w * 4 + tk] = tp;
            topp[t0 + tk] = tp;
        }
    }
    __syncthreads();
    if (tid < 16) {
        int e = sEid[tid];
        float tp = sTp[tid];
        int pos = atomicAdd(&counts[e * 16], 1);
        perm[(e << 13) + pos] = bx * 16 + tid;
        atomicAdd(&sumt[e * 16], tp);
    }
}

// ---------- kernel 2: grouped GEMM — 256x256 tile, BK=64, 8-wave 8-phase ----------
// bid = (tr*8 + tc)*8 + e -> expert == bid%8 == XCD affinity.  Active blocks
// (~256 at balanced routing) = 1 block/CU at 128 KB LDS.
// Per K-tile: 4 phases (mg in {0,1} x ks in {0,1}); each phase:
//   8x ds_read_b128 | 2x global_load_lds (next tile) | s_barrier |
//   setprio(1) 16x MFMA setprio(0) | [vmcnt] | s_barrier
// Staging order of tile t+1 across tile t's phases: A0,A2 | B0,B1 | B2,B3 | A1,A3
//   (A round j covers rows 64j..64j+63; mg=0 needs rounds {0,2}, mg=1 -> {1,3},
//    B needed in full every phase).
// Waits (per-thread ledger): end of ph1 vmcnt(4) -> tile-t A1,A3 landed (6 max
// in flight, pop oldest 2);  end of ph3 vmcnt(2) -> tile-t+1 A0,A2,B0..B3
// landed, its A1,A3 still in flight.  Never drains to 0 in the main loop.
// Last tile re-stages tile NT-1 (garbage, never read) to keep counts uniform.
__global__ void __launch_bounds__(512, 2) moe_gemm_kernel(const u16* __restrict__ xb,
                                                          const u16* __restrict__ Wb,
                                                          const float* __restrict__ bias,
                                                          const int* __restrict__ perm,
                                                          const int* __restrict__ counts,
                                                          const float* __restrict__ topp,
                                                          float* __restrict__ out) {
    // [A buf0 | A buf1 | B buf0 | B buf1], each 16384 u16 = 32 KB; total 128 KB
    __shared__ __align__(16) u16 lds[65536];

    int bid = blockIdx.x;
    int e  = bid & 7;
    int tc = (bid >> 3) & 7;
    int tr = bid >> 6;                       // 0..31
    int cnt = counts[e * 16];
    int row0 = tr << 8;
    if (row0 >= cnt) return;
    int n0 = tc << 8;

    int tid = threadIdx.x;                   // 0..511
    int lane = tid & 63;
    int wid = tid >> 6;                      // 0..7
    int wr = wid >> 2;                       // 0..1  (m half)
    int wc = wid & 3;                        // 0..3  (n quarter)

    const int* permE = perm + (e << 13);
    const u16* WbE = Wb + ((size_t)e << 22);

    // staging: round j = rows 64j..64j+63; slot s = tid + j*512; LDS linear in s,
    // global chunk cg = (s&7)^(r&7) (pre-swizzled source, swizzled ds_read).
    const u16* gA[4];
    const u16* gB[4];
    int sOff[4];
#pragma unroll
    for (int j = 0; j < 4; j++) {
        int s = tid + j * 512;
        int r = s >> 3;                      // row 0..255
        int cg = (s & 7) ^ (r & 7);
        int ta = permE[min(row0 + r, cnt - 1)];
        gA[j] = xb + ((size_t)ta << 11) + (cg << 3);
        gB[j] = WbE + ((size_t)(n0 + r) << 11) + (cg << 3);
        sOff[j] = s * 8;                     // u16 offset (16 B per slot)
    }

#define STG_A(QB, J, KO) load_lds16(gA[J] + (KO), lds + (QB) + sOff[J])
#define STG_B(QB, J, KO) load_lds16(gB[J] + (KO), lds + (QB) + 32768 + sOff[J])
#define VM4 asm volatile("s_waitcnt vmcnt(4)" ::: "memory")
#define VM2 asm volatile("s_waitcnt vmcnt(2)" ::: "memory")
#define VMN ((void)0)

    // prologue: stage tile 0 into buf0, same issue order as steady state
    STG_A(0, 0, 0); STG_A(0, 2, 0);
    STG_B(0, 0, 0); STG_B(0, 1, 0);
    STG_B(0, 2, 0); STG_B(0, 3, 0);
    STG_A(0, 1, 0); STG_A(0, 3, 0);

    int mrow = lane & 15;
    int kq = lane >> 4;
    int s7 = mrow & 7;
    int mb = wr << 7;                        // 0 / 128
    int nb = wc << 6;                        // 0 / 64 / 128 / 192

    f32x4 acc[8][4];
#pragma unroll
    for (int mi = 0; mi < 8; mi++)
#pragma unroll
        for (int ni = 0; ni < 4; ni++)
            acc[mi][ni] = (f32x4){0.0f, 0.0f, 0.0f, 0.0f};

    VM2;                                     // A0,A2,B0..B3 of tile 0 landed
    asm volatile("s_barrier" ::: "memory");

#define PHASE(QB, MG, KS, S1, S2, VMW)                                         \
    {                                                                          \
        int kcs = ((KS) * 4 + kq) ^ s7;                                        \
        const u16* pa = lds + (QB) + ((mb + (MG) * 64 + mrow) * 8 + kcs) * 8;  \
        const u16* pb = lds + (QB) + 32768 + ((nb + mrow) * 8 + kcs) * 8;      \
        bf16x8 a0 = *(const bf16x8*)(pa);                                      \
        bf16x8 a1 = *(const bf16x8*)(pa + 1024);                               \
        bf16x8 a2 = *(const bf16x8*)(pa + 2048);                               \
        bf16x8 a3 = *(const bf16x8*)(pa + 3072);                               \
        bf16x8 b0 = *(const bf16x8*)(pb);                                      \
        bf16x8 b1 = *(const bf16x8*)(pb + 1024);                               \
        bf16x8 b2 = *(const bf16x8*)(pb + 2048);                               \
        bf16x8 b3 = *(const bf16x8*)(pb + 3072);                               \
        S1; S2;                                                                \
        asm volatile("s_barrier" ::: "memory");                                \
        __builtin_amdgcn_s_setprio(1);                                         \
        acc[(MG)*4+0][0] = __builtin_amdgcn_mfma_f32_16x16x32_bf16(a0, b0, acc[(MG)*4+0][0], 0, 0, 0); \
        acc[(MG)*4+0][1] = __builtin_amdgcn_mfma_f32_16x16x32_bf16(a0, b1, acc[(MG)*4+0][1], 0, 0, 0); \
        acc[(MG)*4+0][2] = __builtin_amdgcn_mfma_f32_16x16x32_bf16(a0, b2, acc[(MG)*4+0][2], 0, 0, 0); \
        acc[(MG)*4+0][3] = __builtin_amdgcn_mfma_f32_16x16x32_bf16(a0, b3, acc[(MG)*4+0][3], 0, 0, 0); \
        acc[(MG)*4+1][0] = __builtin_amdgcn_mfma_f32_16x16x32_bf16(a1, b0, acc[(MG)*4+1][0], 0, 0, 0); \
        acc[(MG)*4+1][1] = __builtin_amdgcn_mfma_f32_16x16x32_bf16(a1, b1, acc[(MG)*4+1][1], 0, 0, 0); \
        acc[(MG)*4+1][2] = __builtin_amdgcn_mfma_f32_16x16x32_bf16(a1, b2, acc[(MG)*4+1][2], 0, 0, 0); \
        acc[(MG)*4+1][3] = __builtin_amdgcn_mfma_f32_16x16x32_bf16(a1, b3, acc[(MG)*4+1][3], 0, 0, 0); \
        acc[(MG)*4+2][0] = __builtin_amdgcn_mfma_f32_16x16x32_bf16(a2, b0, acc[(MG)*4+2][0], 0, 0, 0); \
        acc[(MG)*4+2][1] = __builtin_amdgcn_mfma_f32_16x16x32_bf16(a2, b1, acc[(MG)*4+2][1], 0, 0, 0); \
        acc[(MG)*4+2][2] = __builtin_amdgcn_mfma_f32_16x16x32_bf16(a2, b2, acc[(MG)*4+2][2], 0, 0, 0); \
        acc[(MG)*4+2][3] = __builtin_amdgcn_mfma_f32_16x16x32_bf16(a2, b3, acc[(MG)*4+2][3], 0, 0, 0); \
        acc[(MG)*4+3][0] = __builtin_amdgcn_mfma_f32_16x16x32_bf16(a3, b0, acc[(MG)*4+3][0], 0, 0, 0); \
        acc[(MG)*4+3][1] = __builtin_amdgcn_mfma_f32_16x16x32_bf16(a3, b1, acc[(MG)*4+3][1], 0, 0, 0); \
        acc[(MG)*4+3][2] = __builtin_amdgcn_mfma_f32_16x16x32_bf16(a3, b2, acc[(MG)*4+3][2], 0, 0, 0); \
        acc[(MG)*4+3][3] = __builtin_amdgcn_mfma_f32_16x16x32_bf16(a3, b3, acc[(MG)*4+3][3], 0, 0, 0); \
        __builtin_amdgcn_s_setprio(0);                                         \
        VMW;                                                                   \
        asm volatile("s_barrier" ::: "memory");                                \
    }

#pragma unroll 1
    for (int t = 0; t < NT; t += 2) {
        int ko1 = (t + 1) << 6;
        int ko2 = (t + 2 < NT ? t + 2 : NT - 1) << 6;
        // K-tile t in buf0, stage tile t+1 -> buf1
        PHASE(0,     0, 0, STG_A(16384, 0, ko1), STG_A(16384, 2, ko1), VMN);
        PHASE(0,     0, 1, STG_B(16384, 0, ko1), STG_B(16384, 1, ko1), VM4);
        PHASE(0,     1, 0, STG_B(16384, 2, ko1), STG_B(16384, 3, ko1), VMN);
        PHASE(0,     1, 1, STG_A(16384, 1, ko1), STG_A(16384, 3, ko1), VM2);
        // K-tile t+1 in buf1, stage tile t+2 -> buf0
        PHASE(16384, 0, 0, STG_A(0, 0, ko2), STG_A(0, 2, ko2), VMN);
        PHASE(16384, 0, 1, STG_B(0, 0, ko2), STG_B(0, 1, ko2), VM4);
        PHASE(16384, 1, 0, STG_B(0, 2, ko2), STG_B(0, 3, ko2), VMN);
        PHASE(16384, 1, 1, STG_A(0, 1, ko2), STG_A(0, 3, ko2), VM2);
    }

    // epilogue: C/D layout col = lane&15 (n), row = (lane>>4)*4 + reg (m)
    const float* bE = bias + (e << 11);
    float bv[4];
#pragma unroll
    for (int ni = 0; ni < 4; ni++)
        bv[ni] = bE[n0 + nb + ni * 16 + mrow];

    int rb = row0 + mb + ((lane >> 4) << 2);
#pragma unroll
    for (int mi = 0; mi < 8; mi++) {
        int t_[4]; float tp_[4]; int v_[4];
#pragma unroll
        for (int r = 0; r < 4; r++) {
            int gr = rb + mi * 16 + r;
            v_[r] = gr < cnt;
            int grc = v_[r] ? gr : (cnt - 1);
            t_[r] = permE[grc];
            tp_[r] = topp[t_[r]];
        }
#pragma unroll
        for (int ni = 0; ni < 4; ni++) {
            int col = n0 + nb + ni * 16 + mrow;
            f32x4 v = acc[mi][ni];
#pragma unroll
            for (int r = 0; r < 4; r++) {
                if (v_[r])
                    out[((size_t)t_[r] << 11) + col] = (v[r] + bv[ni]) * tp_[r];
            }
        }
    }
}

// ---------- kernel 3: aux loss ----------
__global__ void loss_kernel(const int* __restrict__ counts,
                            const float* __restrict__ sumt,
                            float* __restrict__ lossOut) {
    if (threadIdx.x == 0) {
        float acc = 0.0f;
        for (int e = 0; e < 8; e++) {
            float frac = (float)counts[e * 16] / 8192.0f;
            float prob = sumt[e * 16] / (8192.0f * 8192.0f);
            acc = fmaf(frac, prob, acc);
        }
        lossOut[0] = acc * 3e-6f * 8.0f;
    }
}

extern "C" void kernel_launch(void* const* d_in, const int* in_sizes, int n_in,
                              void* d_out, int out_size, void* d_ws, size_t ws_size,
                              hipStream_t stream) {
    const float* x  = (const float*)d_in[0];   // (4,2048,2048)
    const float* Wr = (const float*)d_in[1];   // (8,2048)
    const float* br = (const float*)d_in[2];   // (8,)
    const float* W  = (const float*)d_in[3];   // (8,2048,2048)
    const float* b  = (const float*)d_in[4];   // (8,2048)
    float* out = (float*)d_out;                // 16777216 y + 1 loss

    char* ws = (char*)d_ws;
    u16* Wb     = (u16*)ws;                      // 67,108,864 B
    u16* xb     = (u16*)(ws + 67108864);         // 33,554,432 B
    int* perm   = (int*)(ws + 100663296);        //    262,144 B (8 x 8192)
    float* topp = (float*)(ws + 100925440);      //     32,768 B
    int* counts = (int*)(ws + 100958208);        //        512 B (padded x16)
    float* sumt = (float*)(ws + 100958720);      //        512 B (padded x16)

    zero_kernel<<<1, 256, 0, stream>>>((u32*)counts);
    // 512 router blocks + 16384 convert blocks, fused to overlap bandwidth
    prep_kernel<<<512 + 16384, 256, 0, stream>>>(x, Wr, br, W, Wb, xb, perm,
                                                 topp, counts, sumt);
    moe_gemm_kernel<<<N_EXP * 8 * 32, 512, 0, stream>>>(xb, Wb, b, perm, counts,
                                                        topp, out);
    loss_kernel<<<1, 64, 0, stream>>>(counts, sumt, out + (size_t)T_TOK * DMODEL);
}

// Round 2
// 365.662 us; speedup vs baseline: 1.1211x; 1.1049x over previous
//
#include <hip/hip_runtime.h>

typedef unsigned short u16;
typedef unsigned int u32;
typedef __attribute__((ext_vector_type(8))) __bf16 bf16x8;
typedef __attribute__((ext_vector_type(4))) float f32x4;

#define T_TOK 8192
#define DMODEL 2048
#define N_EXP 8
#define NT 32        // 2048 / BK, BK=64
#define MTILE 320    // ceil(cnt/320) = 4 for cnt <= 1280  ->  32 items/XCD = 1 round
#define MAX_TR 26    // ceil(8192/320) — correctness for any routing

// ---------- helpers ----------
__device__ __forceinline__ u32 f2bf_bits(float f) {
    u32 u = __builtin_bit_cast(u32, f);
    return (u + 0x7fffu + ((u >> 16) & 1u)) >> 16;   // RNE truncate to bf16
}
__device__ __forceinline__ u32 pack2(float a, float b) {
    return f2bf_bits(a) | (f2bf_bits(b) << 16);
}

__device__ __forceinline__ void load_lds16(const u16* g, u16* l) {
    void* gnc = (void*)g;
    __builtin_amdgcn_global_load_lds(
        (__attribute__((address_space(1))) void*)gnc,
        (__attribute__((address_space(3))) void*)l,
        16, 0, 0);
}

// ---------- kernel 0: zero padded counters ----------
__global__ void zero_kernel(u32* p) {
    p[threadIdx.x] = 0u;   // 256 x 4B = 1024 B (counts 512 + sumt 512)
}

// ---------- kernel 1: fused prep — blocks 0..511 router, 512..16895 W->bf16 ----------
__global__ void __launch_bounds__(256) prep_kernel(const float* __restrict__ x,
                                                   const float* __restrict__ Wr,
                                                   const float* __restrict__ br,
                                                   const float* __restrict__ W,
                                                   u16* __restrict__ Wb,
                                                   u16* __restrict__ xb,
                                                   int* __restrict__ perm,
                                                   float* __restrict__ topp,
                                                   int* __restrict__ counts,
                                                   float* __restrict__ sumt) {
    __shared__ int sEid[16];
    __shared__ float sTp[16];

    int bx = blockIdx.x;
    int tid = threadIdx.x;

    if (bx >= 512) {
        // ---- W fp32 -> bf16 (BW-bound, runs concurrently with router) ----
        size_t i = ((size_t)(bx - 512) * 256 + tid) * 8;
        float4 a = *(const float4*)(W + i);
        float4 c = *(const float4*)(W + i + 4);
        uint4 o;
        o.x = pack2(a.x, a.y);
        o.y = pack2(a.z, a.w);
        o.z = pack2(c.x, c.y);
        o.w = pack2(c.z, c.w);
        *(uint4*)(Wb + i) = o;
        return;
    }

    // ---- router: 4 tokens/wave ----
    int lane = tid & 63;
    int w = tid >> 6;
    int t0 = bx * 16 + w * 4;

    float acc[4][8];
#pragma unroll
    for (int tk = 0; tk < 4; tk++)
#pragma unroll
        for (int e = 0; e < 8; e++) acc[tk][e] = 0.0f;

#pragma unroll
    for (int i = 0; i < 8; i++) {
        int vidx = i * 64 + lane;
        float4 wv[8];
#pragma unroll
        for (int e = 0; e < 8; e++)
            wv[e] = *(const float4*)(Wr + e * DMODEL + vidx * 4);
#pragma unroll
        for (int tk = 0; tk < 4; tk++) {
            int t = t0 + tk;
            float4 xv = ((const float4*)(x + ((size_t)t << 11)))[vidx];
            uint2 pk;
            pk.x = pack2(xv.x, xv.y);
            pk.y = pack2(xv.z, xv.w);
            *(uint2*)(xb + ((size_t)t << 11) + (size_t)vidx * 4) = pk;
#pragma unroll
            for (int e = 0; e < 8; e++) {
                acc[tk][e] = fmaf(xv.x, wv[e].x, fmaf(xv.y, wv[e].y,
                              fmaf(xv.z, wv[e].z, fmaf(xv.w, wv[e].w, acc[tk][e]))));
            }
        }
    }
#pragma unroll
    for (int off = 32; off; off >>= 1)
#pragma unroll
        for (int tk = 0; tk < 4; tk++)
#pragma unroll
            for (int e = 0; e < 8; e++)
                acc[tk][e] += __shfl_xor(acc[tk][e], off, 64);

    if (lane == 0) {
#pragma unroll
        for (int tk = 0; tk < 4; tk++) {
            float lg[8];
#pragma unroll
            for (int e = 0; e < 8; e++) lg[e] = acc[tk][e] + br[e];
            float m = lg[0];
            int am = 0;
#pragma unroll
            for (int e = 1; e < 8; e++)
                if (lg[e] > m) { m = lg[e]; am = e; }
            float s = 0.0f;
#pragma unroll
            for (int e = 0; e < 8; e++) s += __expf(lg[e] - m);
            float tp = 1.0f / s;
            sEid[w * 4 + tk] = am;
            sTp[w * 4 + tk] = tp;
            topp[t0 + tk] = tp;
        }
    }
    __syncthreads();
    if (tid < 16) {
        int e = sEid[tid];
        float tp = sTp[tid];
        int pos = atomicAdd(&counts[e * 16], 1);
        perm[(e << 13) + pos] = bx * 16 + tid;
        atomicAdd(&sumt[e * 16], tp);
    }
}

// ---------- kernel 2: grouped GEMM — 320x256 tile, BK=64, 8-wave, one round/XCD ----------
// bid = (tr*8 + tc)*8 + e -> expert == bid%8 == XCD affinity.
// Active blocks/XCD = ceil(cnt/320) * 8 = 32 for cnt<=1280 -> exactly 1 block/CU,
// a SINGLE dispatch round (R1's 2-round quantization at M=256 was the 2x loss).
// LDS: A 320x64 dbuf (80K) + B 256x64 dbuf (64K) = 144 KB.
// Wave tile 160x64 (2m x 4n waves), acc[2][5][4] f32x4 = 160 accum regs.
// Per K-tile: 4 phases (mg,ks); staging of tile t+1: B0-3 in ph0, A0-3 in ph1,
// A4 in ph2, none in ph3.  Per-wave vmcnt ledger (9 loads/tile):
//   enter ph0: 1 outstanding [A4(t)]
//   ph0 +4 (B0-3 t+1) -> 5, wait none
//   ph1 +4 (A0-3 t+1) -> 9, wait vmcnt(8)  => A4(t) landed (needed in ph2/3)
//   ph2 +1 (A4  t+1) -> 9, wait none
//   ph3 +0           -> 9, wait vmcnt(1)  => B0-3,A0-3(t+1) landed, A4(t+1) flying
// Min slack: 2 phases (A0-3), 3 phases (B, A4) — never drains to 0.
__global__ void __launch_bounds__(512, 2) moe_gemm_kernel(const u16* __restrict__ xb,
                                                          const u16* __restrict__ Wb,
                                                          const float* __restrict__ bias,
                                                          const int* __restrict__ perm,
                                                          const int* __restrict__ counts,
                                                          const float* __restrict__ topp,
                                                          float* __restrict__ out) {
    // [A buf0 | A buf1 | B buf0 | B buf1] = 20480+20480+16384+16384 u16 = 144 KB
    __shared__ __align__(16) u16 lds[73728];

    int bid = blockIdx.x;
    int e  = bid & 7;
    int tc = (bid >> 3) & 7;
    int tr = bid >> 6;                       // 0..MAX_TR-1
    int cnt = counts[e * 16];
    int row0 = tr * MTILE;
    if (row0 >= cnt) return;
    int n0 = tc << 8;

    int tid = threadIdx.x;                   // 0..511
    int lane = tid & 63;
    int wid = tid >> 6;                      // 0..7
    int wr = wid >> 2;                       // 0..1  (m half: 160 rows each)
    int wc = wid & 3;                        // 0..3  (n quarter: 64 cols each)

    const int* permE = perm + (e << 13);
    const u16* WbE = Wb + ((size_t)e << 22);

    // staging round j covers rows 64j..64j+63 (slot s = tid + j*512, r = s>>3);
    // LDS linear in s, global chunk cg = (s&7)^(r&7) (pre-swizzled source).
    const u16* gA[5];
    const u16* gB[4];
    int sOff[5];
#pragma unroll
    for (int j = 0; j < 5; j++) {
        int s = tid + j * 512;
        int r = s >> 3;                      // row 0..319
        int cg = (s & 7) ^ (r & 7);
        int ta = permE[min(row0 + r, cnt - 1)];
        gA[j] = xb + ((size_t)ta << 11) + (cg << 3);
        if (j < 4) gB[j] = WbE + ((size_t)(n0 + r) << 11) + (cg << 3);
        sOff[j] = s * 8;                     // u16 offset (16 B per slot)
    }

#define STG_A(P, J, KO) load_lds16(gA[J] + (KO), lds + (P) * 20480 + sOff[J])
#define STG_B(P, J, KO) load_lds16(gB[J] + (KO), lds + 40960 + (P) * 16384 + sOff[J])
#define SB4(P, KO) { STG_B(P,0,KO); STG_B(P,1,KO); STG_B(P,2,KO); STG_B(P,3,KO); }
#define SA4(P, KO) { STG_A(P,0,KO); STG_A(P,1,KO); STG_A(P,2,KO); STG_A(P,3,KO); }
#define SA1(P, KO) { STG_A(P,4,KO); }
#define VM8 asm volatile("s_waitcnt vmcnt(8)" ::: "memory")
#define VM1 asm volatile("s_waitcnt vmcnt(1)" ::: "memory")
#define VMN ((void)0)

    int mrow = lane & 15;
    int kq = lane >> 4;
    int s7 = mrow & 7;
    int mb = wr * 160;
    int nb = wc << 6;

    f32x4 acc[2][5][4];
#pragma unroll
    for (int mg = 0; mg < 2; mg++)
#pragma unroll
        for (int i = 0; i < 5; i++)
#pragma unroll
            for (int ni = 0; ni < 4; ni++)
                acc[mg][i][ni] = (f32x4){0.0f, 0.0f, 0.0f, 0.0f};

    // prologue: stage tile 0 into buf0 in steady-state queue order
    SB4(0, 0); SA4(0, 0); SA1(0, 0);
    VM1;                                     // B0-3, A0-3 of tile 0 landed
    asm volatile("s_barrier" ::: "memory");

#define MFMA4(MG, I, AV)                                                                     \
    acc[MG][I][0] = __builtin_amdgcn_mfma_f32_16x16x32_bf16(AV, bv0, acc[MG][I][0], 0, 0, 0); \
    acc[MG][I][1] = __builtin_amdgcn_mfma_f32_16x16x32_bf16(AV, bv1, acc[MG][I][1], 0, 0, 0); \
    acc[MG][I][2] = __builtin_amdgcn_mfma_f32_16x16x32_bf16(AV, bv2, acc[MG][I][2], 0, 0, 0); \
    acc[MG][I][3] = __builtin_amdgcn_mfma_f32_16x16x32_bf16(AV, bv3, acc[MG][I][3], 0, 0, 0);

#define PH(PB, MG, KS, STMTS, WAIT)                                            \
    {                                                                          \
        int kcs = ((KS) * 4 + kq) ^ s7;                                        \
        const u16* pa = lds + (PB) * 20480 +                                   \
                        ((mb + (MG) * 80 + mrow) * 8 + kcs) * 8;               \
        const u16* pb = lds + 40960 + (PB) * 16384 +                           \
                        ((nb + mrow) * 8 + kcs) * 8;                           \
        bf16x8 av0 = *(const bf16x8*)(pa);                                     \
        bf16x8 av1 = *(const bf16x8*)(pa + 1024);                              \
        bf16x8 av2 = *(const bf16x8*)(pa + 2048);                              \
        bf16x8 av3 = *(const bf16x8*)(pa + 3072);                              \
        bf16x8 av4 = *(const bf16x8*)(pa + 4096);                              \
        bf16x8 bv0 = *(const bf16x8*)(pb);                                     \
        bf16x8 bv1 = *(const bf16x8*)(pb + 1024);                              \
        bf16x8 bv2 = *(const bf16x8*)(pb + 2048);                              \
        bf16x8 bv3 = *(const bf16x8*)(pb + 3072);                              \
        STMTS;                                                                 \
        asm volatile("s_barrier" ::: "memory");                                \
        __builtin_amdgcn_s_setprio(1);                                         \
        MFMA4((MG), 0, av0)                                                    \
        MFMA4((MG), 1, av1)                                                    \
        MFMA4((MG), 2, av2)                                                    \
        MFMA4((MG), 3, av3)                                                    \
        MFMA4((MG), 4, av4)                                                    \
        __builtin_amdgcn_s_setprio(0);                                         \
        WAIT;                                                                  \
        asm volatile("s_barrier" ::: "memory");                                \
    }

#pragma unroll 1
    for (int t = 0; t < NT; t += 2) {
        int ko1 = (t + 1) << 6;
        int ko2 = (t + 2 < NT ? t + 2 : NT - 1) << 6;   // last: dummy restage
        // K-tile t in buf0, stage tile t+1 -> buf1
        PH(0, 0, 0, SB4(1, ko1), VMN);
        PH(0, 0, 1, SA4(1, ko1), VM8);
        PH(0, 1, 0, SA1(1, ko1), VMN);
        PH(0, 1, 1, ;,           VM1);
        // K-tile t+1 in buf1, stage tile t+2 -> buf0
        PH(1, 0, 0, SB4(0, ko2), VMN);
        PH(1, 0, 1, SA4(0, ko2), VM8);
        PH(1, 1, 0, SA1(0, ko2), VMN);
        PH(1, 1, 1, ;,           VM1);
    }

    // epilogue: C/D layout col = lane&15 (n), row = (lane>>4)*4 + reg (m)
    const float* bE = bias + (e << 11);
    float bvx[4];
#pragma unroll
    for (int ni = 0; ni < 4; ni++)
        bvx[ni] = bE[n0 + nb + ni * 16 + mrow];

#pragma unroll
    for (int mg = 0; mg < 2; mg++)
#pragma unroll
        for (int i = 0; i < 5; i++) {
            int rbase = row0 + mb + mg * 80 + i * 16 + ((lane >> 4) << 2);
            int t_[4]; float tp_[4]; int v_[4];
#pragma unroll
            for (int r = 0; r < 4; r++) {
                int gr = rbase + r;
                v_[r] = gr < cnt;
                int grc = v_[r] ? gr : (cnt - 1);
                t_[r] = permE[grc];
                tp_[r] = topp[t_[r]];
            }
#pragma unroll
            for (int ni = 0; ni < 4; ni++) {
                int col = n0 + nb + ni * 16 + mrow;
                f32x4 v = acc[mg][i][ni];
#pragma unroll
                for (int r = 0; r < 4; r++) {
                    if (v_[r])
                        out[((size_t)t_[r] << 11) + col] = (v[r] + bvx[ni]) * tp_[r];
                }
            }
        }
}

// ---------- kernel 3: aux loss ----------
__global__ void loss_kernel(const int* __restrict__ counts,
                            const float* __restrict__ sumt,
                            float* __restrict__ lossOut) {
    if (threadIdx.x == 0) {
        float acc = 0.0f;
        for (int e = 0; e < 8; e++) {
            float frac = (float)counts[e * 16] / 8192.0f;
            float prob = sumt[e * 16] / (8192.0f * 8192.0f);
            acc = fmaf(frac, prob, acc);
        }
        lossOut[0] = acc * 3e-6f * 8.0f;
    }
}

extern "C" void kernel_launch(void* const* d_in, const int* in_sizes, int n_in,
                              void* d_out, int out_size, void* d_ws, size_t ws_size,
                              hipStream_t stream) {
    const float* x  = (const float*)d_in[0];   // (4,2048,2048)
    const float* Wr = (const float*)d_in[1];   // (8,2048)
    const float* br = (const float*)d_in[2];   // (8,)
    const float* W  = (const float*)d_in[3];   // (8,2048,2048)
    const float* b  = (const float*)d_in[4];   // (8,2048)
    float* out = (float*)d_out;                // 16777216 y + 1 loss

    char* ws = (char*)d_ws;
    u16* Wb     = (u16*)ws;                      // 67,108,864 B
    u16* xb     = (u16*)(ws + 67108864);         // 33,554,432 B
    int* perm   = (int*)(ws + 100663296);        //    262,144 B (8 x 8192)
    float* topp = (float*)(ws + 100925440);      //     32,768 B
    int* counts = (int*)(ws + 100958208);        //        512 B (padded x16)
    float* sumt = (float*)(ws + 100958720);      //        512 B (padded x16)

    zero_kernel<<<1, 256, 0, stream>>>((u32*)counts);
    // 512 router blocks + 16384 convert blocks, fused to overlap bandwidth
    prep_kernel<<<512 + 16384, 256, 0, stream>>>(x, Wr, br, W, Wb, xb, perm,
                                                 topp, counts, sumt);
    moe_gemm_kernel<<<N_EXP * 8 * MAX_TR, 512, 0, stream>>>(xb, Wb, b, perm,
                                                            counts, topp, out);
    loss_kernel<<<1, 64, 0, stream>>>(counts, sumt, out + (size_t)T_TOK * DMODEL);
}

// Round 4
// 353.050 us; speedup vs baseline: 1.1612x; 1.0357x over previous
//
#include <hip/hip_runtime.h>

typedef unsigned short u16;
typedef unsigned int u32;
typedef __attribute__((ext_vector_type(8))) __bf16 bf16x8;
typedef __attribute__((ext_vector_type(4))) float f32x4;
typedef __attribute__((ext_vector_type(2))) u32 u32x2;

#define T_TOK 8192
#define DMODEL 2048
#define N_EXP 8
#define NT 32        // 2048 / BK, BK=64
#define MTILE 320    // ceil(cnt/320) = 4 for cnt <= 1280  ->  32 items/XCD = 1 round
#define MAX_TR 26    // ceil(8192/320) — correctness for any routing

// ---------- helpers ----------
__device__ __forceinline__ u32 f2bf_bits(float f) {
    u32 u = __builtin_bit_cast(u32, f);
    return (u + 0x7fffu + ((u >> 16) & 1u)) >> 16;   // RNE truncate to bf16
}
__device__ __forceinline__ u32 pack2(float a, float b) {
    return f2bf_bits(a) | (f2bf_bits(b) << 16);
}

__device__ __forceinline__ void load_lds16(const u16* g, u16* l) {
    void* gnc = (void*)g;
    __builtin_amdgcn_global_load_lds(
        (__attribute__((address_space(1))) void*)gnc,
        (__attribute__((address_space(3))) void*)l,
        16, 0, 0);
}

// ---------- kernel 1: fused prep — blocks 0..511 router, 512..4607 W->bf16 ----------
__global__ void __launch_bounds__(256) prep_kernel(const float* __restrict__ x,
                                                   const float* __restrict__ Wr,
                                                   const float* __restrict__ br,
                                                   const float* __restrict__ W,
                                                   u16* __restrict__ Wb,
                                                   u16* __restrict__ xb,
                                                   int* __restrict__ perm,
                                                   float* __restrict__ topp,
                                                   int* __restrict__ counts,
                                                   float* __restrict__ sumt) {
    __shared__ int sEid[16];
    __shared__ float sTp[16];

    int bx = blockIdx.x;
    int tid = threadIdx.x;

    if (bx >= 512) {
        // ---- W fp32 -> bf16: 128 B/thread, 8 independent loads in flight.
        // Non-temporal read (W is read exactly once) keeps Wb/xb LLC-resident.
        int cb = bx - 512;                               // 0..4095
        const f32x4* Wp = (const f32x4*)W + (size_t)cb * 2048;
        u32x2* Op = (u32x2*)Wb + (size_t)cb * 2048;
        f32x4 a[8];
#pragma unroll
        for (int j = 0; j < 8; j++)
            a[j] = __builtin_nontemporal_load(Wp + j * 256 + tid);
#pragma unroll
        for (int j = 0; j < 8; j++) {
            u32x2 o;
            o.x = pack2(a[j].x, a[j].y);
            o.y = pack2(a[j].z, a[j].w);
            Op[j * 256 + tid] = o;
        }
        return;
    }

    // ---- router: 4 tokens/wave ----
    int lane = tid & 63;
    int w = tid >> 6;
    int t0 = bx * 16 + w * 4;

    float acc[4][8];
#pragma unroll
    for (int tk = 0; tk < 4; tk++)
#pragma unroll
        for (int e = 0; e < 8; e++) acc[tk][e] = 0.0f;

#pragma unroll
    for (int i = 0; i < 8; i++) {
        int vidx = i * 64 + lane;
        float4 wv[8];
#pragma unroll
        for (int e = 0; e < 8; e++)
            wv[e] = *(const float4*)(Wr + e * DMODEL + vidx * 4);
#pragma unroll
        for (int tk = 0; tk < 4; tk++) {
            int t = t0 + tk;
            float4 xv = ((const float4*)(x + ((size_t)t << 11)))[vidx];
            uint2 pk;
            pk.x = pack2(xv.x, xv.y);
            pk.y = pack2(xv.z, xv.w);
            *(uint2*)(xb + ((size_t)t << 11) + (size_t)vidx * 4) = pk;
#pragma unroll
            for (int e = 0; e < 8; e++) {
                acc[tk][e] = fmaf(xv.x, wv[e].x, fmaf(xv.y, wv[e].y,
                              fmaf(xv.z, wv[e].z, fmaf(xv.w, wv[e].w, acc[tk][e]))));
            }
        }
    }
#pragma unroll
    for (int off = 32; off; off >>= 1)
#pragma unroll
        for (int tk = 0; tk < 4; tk++)
#pragma unroll
            for (int e = 0; e < 8; e++)
                acc[tk][e] += __shfl_xor(acc[tk][e], off, 64);

    if (lane == 0) {
#pragma unroll
        for (int tk = 0; tk < 4; tk++) {
            float lg[8];
#pragma unroll
            for (int e = 0; e < 8; e++) lg[e] = acc[tk][e] + br[e];
            float m = lg[0];
            int am = 0;
#pragma unroll
            for (int e = 1; e < 8; e++)
                if (lg[e] > m) { m = lg[e]; am = e; }
            float s = 0.0f;
#pragma unroll
            for (int e = 0; e < 8; e++) s += __expf(lg[e] - m);
            float tp = 1.0f / s;
            sEid[w * 4 + tk] = am;
            sTp[w * 4 + tk] = tp;
            topp[t0 + tk] = tp;
        }
    }
    __syncthreads();
    if (tid < 16) {
        int e = sEid[tid];
        float tp = sTp[tid];
        int pos = atomicAdd(&counts[e * 16], 1);
        perm[(e << 13) + pos] = bx * 16 + tid;
        atomicAdd(&sumt[e * 16], tp);
    }
}

// ---------- kernel 2: grouped GEMM — 320x256 tile, BK=64, 8-wave, one round/XCD ----------
// bid = (tr*8 + tc)*8 + e -> expert == bid%8 == XCD affinity.
// Active blocks/XCD = ceil(cnt/320) * 8 = 32 for cnt<=1280 -> exactly 1 block/CU,
// a SINGLE dispatch round.  LDS: A 320x64 dbuf (80K) + B 256x64 dbuf (64K) = 144 KB.
// Wave tile 160x64 (2m x 4n waves), acc[2][5][4] f32x4 = 160 accum regs.
// Staging of tile t+1: B0-3 in ph0, A0-3 in ph1, A4 in ph2, none in ph3.
// vmcnt ledger (9 loads/tile): ph1-end vmcnt(8) => A4(t) landed;
// ph3-end vmcnt(1) => B0-3,A0-3(t+1) landed, A4(t+1) still flying.
// Block 0 additionally emits the aux loss (counts/sumt final after prep).
__global__ void __launch_bounds__(512, 2) moe_gemm_kernel(const u16* __restrict__ xb,
                                                          const u16* __restrict__ Wb,
                                                          const float* __restrict__ bias,
                                                          const int* __restrict__ perm,
                                                          const int* __restrict__ counts,
                                                          const float* __restrict__ sumt,
                                                          const float* __restrict__ topp,
                                                          float* __restrict__ out) {
    // [A buf0 | A buf1 | B buf0 | B buf1] = 20480+20480+16384+16384 u16 = 144 KB
    __shared__ __align__(16) u16 lds[73728];

    int bid = blockIdx.x;

    // ---- aux loss (folded former loss_kernel; before any early return) ----
    if (bid == 0 && threadIdx.x == 0) {
        float lacc = 0.0f;
        for (int e = 0; e < 8; e++) {
            float frac = (float)counts[e * 16] / 8192.0f;
            float prob = sumt[e * 16] / (8192.0f * 8192.0f);
            lacc = fmaf(frac, prob, lacc);
        }
        out[(size_t)T_TOK * DMODEL] = lacc * 3e-6f * 8.0f;
    }

    int e  = bid & 7;
    int tc = (bid >> 3) & 7;
    int tr = bid >> 6;                       // 0..MAX_TR-1
    int cnt = counts[e * 16];
    int row0 = tr * MTILE;
    if (row0 >= cnt) return;
    int n0 = tc << 8;

    int tid = threadIdx.x;                   // 0..511
    int lane = tid & 63;
    int wid = tid >> 6;                      // 0..7
    int wr = wid >> 2;                       // 0..1  (m half: 160 rows each)
    int wc = wid & 3;                        // 0..3  (n quarter: 64 cols each)

    const int* permE = perm + (e << 13);
    const u16* WbE = Wb + ((size_t)e << 22);

    // staging round j covers rows 64j..64j+63 (slot s = tid + j*512, r = s>>3);
    // LDS linear in s, global chunk cg = (s&7)^(r&7) (pre-swizzled source).
    const u16* gA[5];
    const u16* gB[4];
    int sOff[5];
#pragma unroll
    for (int j = 0; j < 5; j++) {
        int s = tid + j * 512;
        int r = s >> 3;                      // row 0..319
        int cg = (s & 7) ^ (r & 7);
        int ta = permE[min(row0 + r, cnt - 1)];
        gA[j] = xb + ((size_t)ta << 11) + (cg << 3);
        if (j < 4) gB[j] = WbE + ((size_t)(n0 + r) << 11) + (cg << 3);
        sOff[j] = s * 8;                     // u16 offset (16 B per slot)
    }

#define STG_A(P, J, KO) load_lds16(gA[J] + (KO), lds + (P) * 20480 + sOff[J])
#define STG_B(P, J, KO) load_lds16(gB[J] + (KO), lds + 40960 + (P) * 16384 + sOff[J])
#define SB4(P, KO) { STG_B(P,0,KO); STG_B(P,1,KO); STG_B(P,2,KO); STG_B(P,3,KO); }
#define SA4(P, KO) { STG_A(P,0,KO); STG_A(P,1,KO); STG_A(P,2,KO); STG_A(P,3,KO); }
#define SA1(P, KO) { STG_A(P,4,KO); }
#define VM8 asm volatile("s_waitcnt vmcnt(8)" ::: "memory")
#define VM1 asm volatile("s_waitcnt vmcnt(1)" ::: "memory")
#define VMN ((void)0)

    int mrow = lane & 15;
    int kq = lane >> 4;
    int s7 = mrow & 7;
    int mb = wr * 160;
    int nb = wc << 6;

    f32x4 acc[2][5][4];
#pragma unroll
    for (int mg = 0; mg < 2; mg++)
#pragma unroll
        for (int i = 0; i < 5; i++)
#pragma unroll
            for (int ni = 0; ni < 4; ni++)
                acc[mg][i][ni] = (f32x4){0.0f, 0.0f, 0.0f, 0.0f};

    // prologue: stage tile 0 into buf0 in steady-state queue order
    SB4(0, 0); SA4(0, 0); SA1(0, 0);
    VM1;                                     // B0-3, A0-3 of tile 0 landed
    asm volatile("s_barrier" ::: "memory");

#define MFMA4(MG, I, AV)                                                                     \
    acc[MG][I][0] = __builtin_amdgcn_mfma_f32_16x16x32_bf16(AV, bv0, acc[MG][I][0], 0, 0, 0); \
    acc[MG][I][1] = __builtin_amdgcn_mfma_f32_16x16x32_bf16(AV, bv1, acc[MG][I][1], 0, 0, 0); \
    acc[MG][I][2] = __builtin_amdgcn_mfma_f32_16x16x32_bf16(AV, bv2, acc[MG][I][2], 0, 0, 0); \
    acc[MG][I][3] = __builtin_amdgcn_mfma_f32_16x16x32_bf16(AV, bv3, acc[MG][I][3], 0, 0, 0);

#define PH(PB, MG, KS, STMTS, WAIT)                                            \
    {                                                                          \
        int kcs = ((KS) * 4 + kq) ^ s7;                                        \
        const u16* pa = lds + (PB) * 20480 +                                   \
                        ((mb + (MG) * 80 + mrow) * 8 + kcs) * 8;               \
        const u16* pb = lds + 40960 + (PB) * 16384 +                           \
                        ((nb + mrow) * 8 + kcs) * 8;                           \
        bf16x8 av0 = *(const bf16x8*)(pa);                                     \
        bf16x8 av1 = *(const bf16x8*)(pa + 1024);                              \
        bf16x8 av2 = *(const bf16x8*)(pa + 2048);                              \
        bf16x8 av3 = *(const bf16x8*)(pa + 3072);                              \
        bf16x8 av4 = *(const bf16x8*)(pa + 4096);                              \
        bf16x8 bv0 = *(const bf16x8*)(pb);                                     \
        bf16x8 bv1 = *(const bf16x8*)(pb + 1024);                              \
        bf16x8 bv2 = *(const bf16x8*)(pb + 2048);                              \
        bf16x8 bv3 = *(const bf16x8*)(pb + 3072);                              \
        STMTS;                                                                 \
        asm volatile("s_barrier" ::: "memory");                                \
        __builtin_amdgcn_s_setprio(1);                                         \
        MFMA4((MG), 0, av0)                                                    \
        MFMA4((MG), 1, av1)                                                    \
        MFMA4((MG), 2, av2)                                                    \
        MFMA4((MG), 3, av3)                                                    \
        MFMA4((MG), 4, av4)                                                    \
        __builtin_amdgcn_s_setprio(0);                                         \
        WAIT;                                                                  \
        asm volatile("s_barrier" ::: "memory");                                \
    }

#pragma unroll 1
    for (int t = 0; t < NT; t += 2) {
        int ko1 = (t + 1) << 6;
        int ko2 = (t + 2 < NT ? t + 2 : NT - 1) << 6;   // last: dummy restage
        // K-tile t in buf0, stage tile t+1 -> buf1
        PH(0, 0, 0, SB4(1, ko1), VMN);
        PH(0, 0, 1, SA4(1, ko1), VM8);
        PH(0, 1, 0, SA1(1, ko1), VMN);
        PH(0, 1, 1, ;,           VM1);
        // K-tile t+1 in buf1, stage tile t+2 -> buf0
        PH(1, 0, 0, SB4(0, ko2), VMN);
        PH(1, 0, 1, SA4(0, ko2), VM8);
        PH(1, 1, 0, SA1(0, ko2), VMN);
        PH(1, 1, 1, ;,           VM1);
    }

    // epilogue: C/D layout col = lane&15 (n), row = (lane>>4)*4 + reg (m)
    const float* bE = bias + (e << 11);
    float bvx[4];
#pragma unroll
    for (int ni = 0; ni < 4; ni++)
        bvx[ni] = bE[n0 + nb + ni * 16 + mrow];

#pragma unroll
    for (int mg = 0; mg < 2; mg++)
#pragma unroll
        for (int i = 0; i < 5; i++) {
            int rbase = row0 + mb + mg * 80 + i * 16 + ((lane >> 4) << 2);
            int t_[4]; float tp_[4]; int v_[4];
#pragma unroll
            for (int r = 0; r < 4; r++) {
                int gr = rbase + r;
                v_[r] = gr < cnt;
                int grc = v_[r] ? gr : (cnt - 1);
                t_[r] = permE[grc];
                tp_[r] = topp[t_[r]];
            }
#pragma unroll
            for (int ni = 0; ni < 4; ni++) {
                int col = n0 + nb + ni * 16 + mrow;
                f32x4 v = acc[mg][i][ni];
#pragma unroll
                for (int r = 0; r < 4; r++) {
                    if (v_[r])
                        out[((size_t)t_[r] << 11) + col] = (v[r] + bvx[ni]) * tp_[r];
                }
            }
        }
}

extern "C" void kernel_launch(void* const* d_in, const int* in_sizes, int n_in,
                              void* d_out, int out_size, void* d_ws, size_t ws_size,
                              hipStream_t stream) {
    const float* x  = (const float*)d_in[0];   // (4,2048,2048)
    const float* Wr = (const float*)d_in[1];   // (8,2048)
    const float* br = (const float*)d_in[2];   // (8,)
    const float* W  = (const float*)d_in[3];   // (8,2048,2048)
    const float* b  = (const float*)d_in[4];   // (8,2048)
    float* out = (float*)d_out;                // 16777216 y + 1 loss

    char* ws = (char*)d_ws;
    u16* Wb     = (u16*)ws;                      // 67,108,864 B
    u16* xb     = (u16*)(ws + 67108864);         // 33,554,432 B
    int* perm   = (int*)(ws + 100663296);        //    262,144 B (8 x 8192)
    float* topp = (float*)(ws + 100925440);      //     32,768 B
    int* counts = (int*)(ws + 100958208);        //        512 B (padded x16)
    float* sumt = (float*)(ws + 100958720);      //        512 B (padded x16, contiguous after counts)

    (void)hipMemsetAsync(counts, 0, 1024, stream);   // counts + sumt in one memset
    // 512 router blocks + 4096 convert blocks (128 B/thread), fused
    prep_kernel<<<512 + 4096, 256, 0, stream>>>(x, Wr, br, W, Wb, xb, perm,
                                                topp, counts, sumt);
    moe_gemm_kernel<<<N_EXP * 8 * MAX_TR, 512, 0, stream>>>(xb, Wb, b, perm,
                                                            counts, sumt, topp, out);
}